// Round 1
// baseline (289.268 us; speedup 1.0000x reference)
//
#include <hip/hip_runtime.h>
#include <math.h>

#define B 2048
#define D 64
#define IT 8

static __device__ __forceinline__ float exp2fast(float x) { return __builtin_amdgcn_exp2f(x); }
static __device__ __forceinline__ float log2fast(float x) { return __builtin_amdgcn_logf(x); }

// ---------------------------------------------------------------------------
// Kernel 1: precompute packed per-(j,d) constants, C2[j] row sums, kl sum.
//   h  = -0.5*log2e*exp(-lv)         (so lp2 = t*t*h + c, in log2 units)
//   c  = -0.5*log2e*(lv + ln(2*pi))
//   pack4[j*D+d]  = (mu, h, c, 0)          row-major, for loop 1
//   pack2[d*B+j]  = (mu, h)                transposed, for loop 2
//   C2[j] = sum_d c                        folded constant for s2 rows
// ---------------------------------------------------------------------------
__global__ __launch_bounds__(64) void k_pre(
    const float* __restrict__ kl, const float* __restrict__ zm,
    const float* __restrict__ zlv,
    float4* __restrict__ pack4, float2* __restrict__ pack2,
    float* __restrict__ C2, float* __restrict__ out)
{
    const float LOG2E   = 1.4426950408889634f;
    const float LOG_2PI = 1.8378770664093453f;
    int j = blockIdx.x, d = threadIdx.x;
    int idx = j * D + d;
    float lv = zlv[idx];
    float mu = zm[idx];
    float is = exp2fast(-LOG2E * lv);            // e^{-lv}
    float h  = -0.5f * LOG2E * is;
    float cv = -0.5f * LOG2E * (lv + LOG_2PI);
    pack4[idx]       = make_float4(mu, h, cv, 0.0f);
    pack2[d * B + j] = make_float2(mu, h);

    float cs = cv, ks = kl[idx];
#pragma unroll
    for (int off = 32; off; off >>= 1) {
        cs += __shfl_xor(cs, off);
        ks += __shfl_xor(ks, off);
    }
    if (d == 0) {
        C2[j] = cs;
        atomicAdd(out, ks);   // kl_loss contribution
    }
}

// ---------------------------------------------------------------------------
// Kernel 2: the 2048x2048x64 workhorse. One wave handles IT=8 rows i and one
// j-chunk of size CJ = B/NC.
//   Loop 1 (lanes own d): acc_d[i] = sum_j 2^{lp2}   (unstabilized, safe)
//   Loop 2 (lanes own j): s2_j[i]  = C2_j + sum_d t*t*h   (lane-local),
//                         then online base-2 LSE per lane, wave-merged.
// ---------------------------------------------------------------------------
__global__ __launch_bounds__(256) void k_main(
    const float* __restrict__ z, const float4* __restrict__ pack4,
    const float2* __restrict__ pack2, const float* __restrict__ C2,
    float* __restrict__ acc, float* __restrict__ wsM, float* __restrict__ wsL,
    int NC, int ncShift)
{
    int lane   = threadIdx.x & 63;
    int wid    = blockIdx.x * 4 + (threadIdx.x >> 6);
    int chunk  = wid & (NC - 1);
    int igroup = wid >> ncShift;
    int i0     = igroup * IT;
    int CJ     = B >> ncShift;
    int j0     = chunk * CJ;

    float zr[IT], a[IT];
#pragma unroll
    for (int k = 0; k < IT; ++k) {
        zr[k] = z[(i0 + k) * D + lane];
        a[k]  = 0.0f;
    }

    // ---- Loop 1: per-dimension sum of exponentials (lanes = d) ----
    for (int j = j0; j < j0 + CJ; ++j) {
        float4 p = pack4[j * D + lane];
#pragma unroll
        for (int k = 0; k < IT; ++k) {
            float t = zr[k] - p.x;
            a[k] += exp2fast(fmaf(t * t, p.y, p.z));
        }
    }
#pragma unroll
    for (int k = 0; k < IT; ++k)
        acc[chunk * (B * D) + (i0 + k) * D + lane] = a[k];

    // ---- Loop 2: per-(i,j) row sums over d (lanes = j), online LSE ----
    float m[IT], l[IT];
#pragma unroll
    for (int k = 0; k < IT; ++k) { m[k] = -3.0e38f; l[k] = 0.0f; }

    for (int jg = 0; jg < (CJ >> 6); ++jg) {
        int jj = j0 + jg * 64 + lane;
        float c2j = C2[jj];
        float s2[IT];
#pragma unroll
        for (int k = 0; k < IT; ++k) s2[k] = c2j;

        for (int d = 0; d < D; ++d) {
            float2 p = pack2[d * B + jj];
#pragma unroll
            for (int k = 0; k < IT; ++k) {
                float zv = __uint_as_float(
                    __builtin_amdgcn_readlane(__float_as_uint(zr[k]), d));
                float t = zv - p.x;
                s2[k] = fmaf(t * t, p.y, s2[k]);
            }
        }
        // one online-LSE step per lane per group (base 2)
#pragma unroll
        for (int k = 0; k < IT; ++k) {
            float delta = s2[k] - m[k];
            float e = exp2fast(-fabsf(delta));
            l[k] = (delta <= 0.0f) ? (l[k] + e) : fmaf(l[k], e, 1.0f);
            m[k] = fmaxf(m[k], s2[k]);
        }
    }

    // wave-level LSE merge (butterfly)
#pragma unroll
    for (int off = 32; off; off >>= 1) {
#pragma unroll
        for (int k = 0; k < IT; ++k) {
            float m2 = __shfl_xor(m[k], off);
            float l2 = __shfl_xor(l[k], off);
            float M  = fmaxf(m[k], m2);
            l[k] = fmaf(l[k], exp2fast(m[k] - M), l2 * exp2fast(m2 - M));
            m[k] = M;
        }
    }
    if (lane == 0) {
#pragma unroll
        for (int k = 0; k < IT; ++k) {
            wsM[(i0 + k) * NC + chunk] = m[k];
            wsL[(i0 + k) * NC + chunk] = l[k];
        }
    }
}

// ---------------------------------------------------------------------------
// Kernel 3: per-i finalization. Merge j-chunks, take logs, reduce over i,
// atomically add (beta-1)*mean(log_qz - log_qz_product) into out.
// ---------------------------------------------------------------------------
__global__ __launch_bounds__(256) void k_fin(
    const float* __restrict__ acc, const float* __restrict__ wsM,
    const float* __restrict__ wsL, float* __restrict__ out, int NC)
{
    const float LN2 = 0.6931471805599453f;
    int i = blockIdx.x * 256 + threadIdx.x;

    // log_qz_product (in log2 units)
    float lqp2 = 0.0f;
    for (int d = 0; d < D; ++d) {
        float s = 0.0f;
        for (int c = 0; c < NC; ++c) s += acc[c * (B * D) + i * D + d];
        lqp2 += log2fast(s);
    }

    // log_qz: merge chunk-level (M, L) pairs
    float M = -3.0e38f, L = 0.0f;
    for (int c = 0; c < NC; ++c) {
        float mc = wsM[i * NC + c], lc = wsL[i * NC + c];
        float Mn = fmaxf(M, mc);
        L = fmaf(L, exp2fast(M - Mn), lc * exp2fast(mc - Mn));
        M = Mn;
    }
    float v = (M + log2fast(L) - lqp2) * LN2;   // ln(qz) - ln(qz_product)

#pragma unroll
    for (int off = 32; off; off >>= 1) v += __shfl_xor(v, off);
    if ((threadIdx.x & 63) == 0)
        atomicAdd(out, v * (5.0f / 2048.0f));   // (BETA-1)/B
}

// ---------------------------------------------------------------------------
extern "C" void kernel_launch(void* const* d_in, const int* in_sizes, int n_in,
                              void* d_out, int out_size, void* d_ws, size_t ws_size,
                              hipStream_t stream)
{
    const float* kl  = (const float*)d_in[0];
    const float* zm  = (const float*)d_in[1];
    const float* zlv = (const float*)d_in[2];
    const float* zs  = (const float*)d_in[3];
    float* out = (float*)d_out;
    float* ws  = (float*)d_ws;

    // pick j-chunk count NC (power of two) that fits the workspace
    size_t wsFloats = ws_size / sizeof(float);
    int NC = 16;
    while (NC > 1) {
        size_t need = (size_t)4 * B * D        // pack4
                    + (size_t)2 * B * D        // pack2
                    + B                        // C2
                    + (size_t)2 * B * NC       // wsM + wsL
                    + (size_t)NC * B * D;      // acc partials
        if (need <= wsFloats) break;
        NC >>= 1;
    }
    int ncShift = 0;
    while ((1 << ncShift) < NC) ++ncShift;

    float4* pack4 = (float4*)ws;                      // 4*B*D floats
    float2* pack2 = (float2*)(ws + 4 * B * D);        // 2*B*D floats
    float*  C2    = ws + 6 * B * D;                   // B floats
    float*  wsM   = C2 + B;                           // B*NC
    float*  wsL   = wsM + (size_t)B * NC;             // B*NC
    float*  acc   = wsL + (size_t)B * NC;             // NC*B*D

    hipMemsetAsync(d_out, 0, sizeof(float), stream);
    k_pre<<<B, D, 0, stream>>>(kl, zm, zlv, pack4, pack2, C2, out);
    k_main<<<64 * NC, 256, 0, stream>>>(zs, pack4, pack2, C2, acc, wsM, wsL, NC, ncShift);
    k_fin<<<B / 256, 256, 0, stream>>>(acc, wsM, wsL, out, NC);
}

// Round 2
// 288.692 us; speedup vs baseline: 1.0020x; 1.0020x over previous
//
#include <hip/hip_runtime.h>
#include <math.h>

#define B 2048
#define D 64
#define IT 8

static __device__ __forceinline__ float exp2fast(float x) { return __builtin_amdgcn_exp2f(x); }
static __device__ __forceinline__ float log2fast(float x) { return __builtin_amdgcn_logf(x); }

// ---------------------------------------------------------------------------
// Kernel 1: precompute packed per-(j,d) constants, C2[j] row sums, kl sum.
//   h  = -0.5*log2e*exp(-lv)         (so lp2 = t*t*h + c, in log2 units)
//   c  = -0.5*log2e*(lv + ln(2*pi))
//   pack4[j*D+d]  = (mu, h, c, 0)          row-major, for loop 1
//   pack2[d*B+j]  = (mu, h)                transposed, for loop 2
//   C2[j] = sum_d c                        folded constant for s2 rows
// ---------------------------------------------------------------------------
__global__ __launch_bounds__(64) void k_pre(
    const float* __restrict__ kl, const float* __restrict__ zm,
    const float* __restrict__ zlv,
    float4* __restrict__ pack4, float2* __restrict__ pack2,
    float* __restrict__ C2, float* __restrict__ out)
{
    const float LOG2E   = 1.4426950408889634f;
    const float LOG_2PI = 1.8378770664093453f;
    int j = blockIdx.x, d = threadIdx.x;
    int idx = j * D + d;
    float lv = zlv[idx];
    float mu = zm[idx];
    float is = exp2fast(-LOG2E * lv);            // e^{-lv}
    float h  = -0.5f * LOG2E * is;
    float cv = -0.5f * LOG2E * (lv + LOG_2PI);
    pack4[idx]       = make_float4(mu, h, cv, 0.0f);
    pack2[d * B + j] = make_float2(mu, h);

    float cs = cv, ks = kl[idx];
#pragma unroll
    for (int off = 32; off; off >>= 1) {
        cs += __shfl_xor(cs, off);
        ks += __shfl_xor(ks, off);
    }
    if (d == 0) {
        C2[j] = cs;
        atomicAdd(out, ks);   // kl_loss contribution
    }
}

// ---------------------------------------------------------------------------
// Kernel 2: the 2048x2048x64 workhorse. One wave handles IT=8 rows i and one
// j-chunk of size CJ = B/NC.
//   Loop 1 (lanes own d): acc_d[i] = sum_j 2^{lp2}   (unstabilized, safe)
//   Loop 2 (lanes own j): s2_j[i]  = C2_j + sum_d t*t*h   (lane-local),
//                         then online base-2 LSE per lane, wave-merged.
// ---------------------------------------------------------------------------
__global__ __launch_bounds__(256) void k_main(
    const float* __restrict__ z, const float4* __restrict__ pack4,
    const float2* __restrict__ pack2, const float* __restrict__ C2,
    float* __restrict__ acc, float* __restrict__ wsM, float* __restrict__ wsL,
    int NC, int ncShift)
{
    int lane   = threadIdx.x & 63;
    int wid    = blockIdx.x * 4 + (threadIdx.x >> 6);
    int chunk  = wid & (NC - 1);
    int igroup = wid >> ncShift;
    int i0     = igroup * IT;
    int CJ     = B >> ncShift;
    int j0     = chunk * CJ;

    float zr[IT], a[IT];
#pragma unroll
    for (int k = 0; k < IT; ++k) {
        zr[k] = z[(i0 + k) * D + lane];
        a[k]  = 0.0f;
    }

    // ---- Loop 1: per-dimension sum of exponentials (lanes = d) ----
    for (int j = j0; j < j0 + CJ; ++j) {
        float4 p = pack4[j * D + lane];
#pragma unroll
        for (int k = 0; k < IT; ++k) {
            float t = zr[k] - p.x;
            a[k] += exp2fast(fmaf(t * t, p.y, p.z));
        }
    }
#pragma unroll
    for (int k = 0; k < IT; ++k)
        acc[chunk * (B * D) + (i0 + k) * D + lane] = a[k];

    // ---- Loop 2: per-(i,j) row sums over d (lanes = j), online LSE ----
    float m[IT], l[IT];
#pragma unroll
    for (int k = 0; k < IT; ++k) { m[k] = -3.0e38f; l[k] = 0.0f; }

    for (int jg = 0; jg < (CJ >> 6); ++jg) {
        int jj = j0 + jg * 64 + lane;
        float c2j = C2[jj];
        float s2[IT];
#pragma unroll
        for (int k = 0; k < IT; ++k) s2[k] = c2j;

        for (int d = 0; d < D; ++d) {
            float2 p = pack2[d * B + jj];
#pragma unroll
            for (int k = 0; k < IT; ++k) {
                float zv = __uint_as_float(
                    __builtin_amdgcn_readlane(__float_as_uint(zr[k]), d));
                float t = zv - p.x;
                s2[k] = fmaf(t * t, p.y, s2[k]);
            }
        }
        // one online-LSE step per lane per group (base 2)
#pragma unroll
        for (int k = 0; k < IT; ++k) {
            float delta = s2[k] - m[k];
            float e = exp2fast(-fabsf(delta));
            l[k] = (delta <= 0.0f) ? (l[k] + e) : fmaf(l[k], e, 1.0f);
            m[k] = fmaxf(m[k], s2[k]);
        }
    }

    // wave-level LSE merge (butterfly)
#pragma unroll
    for (int off = 32; off; off >>= 1) {
#pragma unroll
        for (int k = 0; k < IT; ++k) {
            float m2 = __shfl_xor(m[k], off);
            float l2 = __shfl_xor(l[k], off);
            float M  = fmaxf(m[k], m2);
            l[k] = fmaf(l[k], exp2fast(m[k] - M), l2 * exp2fast(m2 - M));
            m[k] = M;
        }
    }
    if (lane == 0) {
#pragma unroll
        for (int k = 0; k < IT; ++k) {
            wsM[(i0 + k) * NC + chunk] = m[k];
            wsL[(i0 + k) * NC + chunk] = l[k];
        }
    }
}

// ---------------------------------------------------------------------------
// Kernel 3: per-i finalization. Merge j-chunks, take logs, reduce over i,
// atomically add (beta-1)*mean(log_qz - log_qz_product) into out.
// ---------------------------------------------------------------------------
__global__ __launch_bounds__(256) void k_fin(
    const float* __restrict__ acc, const float* __restrict__ wsM,
    const float* __restrict__ wsL, float* __restrict__ out, int NC)
{
    const float LN2 = 0.6931471805599453f;
    int i = blockIdx.x * 256 + threadIdx.x;

    // log_qz_product (in log2 units)
    float lqp2 = 0.0f;
    for (int d = 0; d < D; ++d) {
        float s = 0.0f;
        for (int c = 0; c < NC; ++c) s += acc[c * (B * D) + i * D + d];
        lqp2 += log2fast(s);
    }

    // log_qz: merge chunk-level (M, L) pairs
    float M = -3.0e38f, L = 0.0f;
    for (int c = 0; c < NC; ++c) {
        float mc = wsM[i * NC + c], lc = wsL[i * NC + c];
        float Mn = fmaxf(M, mc);
        L = fmaf(L, exp2fast(M - Mn), lc * exp2fast(mc - Mn));
        M = Mn;
    }
    float v = (M + log2fast(L) - lqp2) * LN2;   // ln(qz) - ln(qz_product)

#pragma unroll
    for (int off = 32; off; off >>= 1) v += __shfl_xor(v, off);
    if ((threadIdx.x & 63) == 0)
        atomicAdd(out, v * (5.0f / 2048.0f));   // (BETA-1)/B
}

// ---------------------------------------------------------------------------
extern "C" void kernel_launch(void* const* d_in, const int* in_sizes, int n_in,
                              void* d_out, int out_size, void* d_ws, size_t ws_size,
                              hipStream_t stream)
{
    const float* kl  = (const float*)d_in[0];
    const float* zm  = (const float*)d_in[1];
    const float* zlv = (const float*)d_in[2];
    const float* zs  = (const float*)d_in[3];
    float* out = (float*)d_out;
    float* ws  = (float*)d_ws;

    // pick j-chunk count NC (power of two) that fits the workspace
    size_t wsFloats = ws_size / sizeof(float);
    int NC = 16;
    while (NC > 1) {
        size_t need = (size_t)4 * B * D        // pack4
                    + (size_t)2 * B * D        // pack2
                    + B                        // C2
                    + (size_t)2 * B * NC       // wsM + wsL
                    + (size_t)NC * B * D;      // acc partials
        if (need <= wsFloats) break;
        NC >>= 1;
    }
    int ncShift = 0;
    while ((1 << ncShift) < NC) ++ncShift;

    float4* pack4 = (float4*)ws;                      // 4*B*D floats
    float2* pack2 = (float2*)(ws + 4 * B * D);        // 2*B*D floats
    float*  C2    = ws + 6 * B * D;                   // B floats
    float*  wsM   = C2 + B;                           // B*NC
    float*  wsL   = wsM + (size_t)B * NC;             // B*NC
    float*  acc   = wsL + (size_t)B * NC;             // NC*B*D

    hipMemsetAsync(d_out, 0, sizeof(float), stream);
    k_pre<<<B, D, 0, stream>>>(kl, zm, zlv, pack4, pack2, C2, out);
    k_main<<<64 * NC, 256, 0, stream>>>(zs, pack4, pack2, C2, acc, wsM, wsL, NC, ncShift);
    k_fin<<<B / 256, 256, 0, stream>>>(acc, wsM, wsL, out, NC);
}

// Round 3
// 127.669 us; speedup vs baseline: 2.2658x; 2.2613x over previous
//
#include <hip/hip_runtime.h>
#include <math.h>

#define B 2048
#define D 64
#define IT 8

static __device__ __forceinline__ float exp2fast(float x) { return __builtin_amdgcn_exp2f(x); }
static __device__ __forceinline__ float log2fast(float x) { return __builtin_amdgcn_logf(x); }

// ---------------------------------------------------------------------------
// Kernel 1: precompute packed per-(j,d) constants, C2[j] row sums, kl sum.
// All in log2 units:  lp2 = h*(z-mu)^2 + c  =  h*z^2 + g*z + q
//   h = -0.5*log2e*exp(-lv),  g = -2*mu*h,  q = mu^2*h + c,
//   c = -0.5*log2e*(lv + ln(2*pi))
//   pack4[j*D+d] = (h, g, q, 0)   row-major, for loop 1
//   pack2[d*B+j] = (mu, h)        transposed, for loop 2
//   C2[j] = sum_d c
// 256 threads = 4 waves = 4 j rows per block; 1 atomic per block for kl.
// ---------------------------------------------------------------------------
__global__ __launch_bounds__(256) void k_pre(
    const float* __restrict__ kl, const float* __restrict__ zm,
    const float* __restrict__ zlv,
    float4* __restrict__ pack4, float2* __restrict__ pack2,
    float* __restrict__ C2, float* __restrict__ out)
{
    const float LOG2E   = 1.4426950408889634f;
    const float LOG_2PI = 1.8378770664093453f;
    __shared__ float red[4];
    int wv = threadIdx.x >> 6, d = threadIdx.x & 63;
    int j = blockIdx.x * 4 + wv;
    int idx = j * D + d;
    float lv = zlv[idx];
    float mu = zm[idx];
    float is = exp2fast(-LOG2E * lv);            // e^{-lv}
    float h  = -0.5f * LOG2E * is;
    float cv = -0.5f * LOG2E * (lv + LOG_2PI);
    float g  = -2.0f * mu * h;
    float q  = fmaf(mu * mu, h, cv);
    pack4[idx]       = make_float4(h, g, q, 0.0f);
    pack2[d * B + j] = make_float2(mu, h);

    float cs = cv, ks = kl[idx];
#pragma unroll
    for (int off = 32; off; off >>= 1) {
        cs += __shfl_xor(cs, off);
        ks += __shfl_xor(ks, off);
    }
    if (d == 0) {
        C2[j] = cs;
        red[wv] = ks;
    }
    __syncthreads();
    if (threadIdx.x == 0)
        atomicAdd(out, red[0] + red[1] + red[2] + red[3]);  // kl_loss
}

// ---------------------------------------------------------------------------
// Kernel 2: the 2048x2048x64 workhorse. One wave handles IT=8 rows i and one
// j-chunk of size CJ = B/NC.
//   Loop 1 (lanes own d): acc_d[i] = sum_j 2^{h z^2 + g z + q}  (unstabilized,
//          safe: terms bounded and max is O(1))
//   Loop 2 (lanes own j): s2_j[i] = C2_j + sum_d t*t*h  (lane-local),
//          then online base-2 LSE once per 64-j group, wave-merged.
// ---------------------------------------------------------------------------
__global__ __launch_bounds__(256) void k_main(
    const float* __restrict__ z, const float4* __restrict__ pack4,
    const float2* __restrict__ pack2, const float* __restrict__ C2,
    float* __restrict__ acc, float* __restrict__ wsM, float* __restrict__ wsL,
    int NC, int ncShift)
{
    int lane   = threadIdx.x & 63;
    int wid    = blockIdx.x * 4 + (threadIdx.x >> 6);
    int chunk  = wid & (NC - 1);
    int igroup = wid >> ncShift;
    int i0     = igroup * IT;
    int CJ     = B >> ncShift;
    int j0     = chunk * CJ;

    float zr[IT], zr2[IT], a[IT];
#pragma unroll
    for (int k = 0; k < IT; ++k) {
        zr[k]  = z[(i0 + k) * D + lane];
        zr2[k] = zr[k] * zr[k];
        a[k]   = 0.0f;
    }

    // ---- Loop 1: per-dimension sum of exponentials (lanes = d) ----
    for (int j = j0; j < j0 + CJ; ++j) {
        float4 p = pack4[j * D + lane];
#pragma unroll
        for (int k = 0; k < IT; ++k)
            a[k] += exp2fast(fmaf(zr2[k], p.x, fmaf(zr[k], p.y, p.z)));
    }
#pragma unroll
    for (int k = 0; k < IT; ++k)
        acc[chunk * (B * D) + (i0 + k) * D + lane] = a[k];

    // ---- Loop 2: per-(i,j) row sums over d (lanes = j), online LSE ----
    float m[IT], l[IT];
#pragma unroll
    for (int k = 0; k < IT; ++k) { m[k] = -3.0e38f; l[k] = 0.0f; }

    for (int jg = 0; jg < (CJ >> 6); ++jg) {
        int jj = j0 + jg * 64 + lane;
        float c2j = C2[jj];
        float s2[IT];
#pragma unroll
        for (int k = 0; k < IT; ++k) s2[k] = c2j;

        for (int d = 0; d < D; ++d) {
            float2 p = pack2[d * B + jj];
#pragma unroll
            for (int k = 0; k < IT; ++k) {
                float zv = __uint_as_float(
                    __builtin_amdgcn_readlane(__float_as_uint(zr[k]), d));
                float t = zv - p.x;
                s2[k] = fmaf(t * t, p.y, s2[k]);
            }
        }
        // one online-LSE step per lane per group (base 2)
#pragma unroll
        for (int k = 0; k < IT; ++k) {
            float delta = s2[k] - m[k];
            float e = exp2fast(-fabsf(delta));
            l[k] = (delta <= 0.0f) ? (l[k] + e) : fmaf(l[k], e, 1.0f);
            m[k] = fmaxf(m[k], s2[k]);
        }
    }

    // wave-level LSE merge (butterfly)
#pragma unroll
    for (int off = 32; off; off >>= 1) {
#pragma unroll
        for (int k = 0; k < IT; ++k) {
            float m2 = __shfl_xor(m[k], off);
            float l2 = __shfl_xor(l[k], off);
            float M  = fmaxf(m[k], m2);
            l[k] = fmaf(l[k], exp2fast(m[k] - M), l2 * exp2fast(m2 - M));
            m[k] = M;
        }
    }
    if (lane == 0) {
#pragma unroll
        for (int k = 0; k < IT; ++k) {
            wsM[(i0 + k) * NC + chunk] = m[k];
            wsL[(i0 + k) * NC + chunk] = l[k];
        }
    }
}

// ---------------------------------------------------------------------------
// Kernel 3: per-i finalization, one WAVE per i (512 blocks x 256 threads).
//   lanes own d: chunk-sum acc (coalesced), log2, butterfly-sum -> lqp2
//   lanes own c: merge chunk (M,L) pairs via butterfly LSE
//   block LDS reduce -> 1 atomic per block
// ---------------------------------------------------------------------------
__global__ __launch_bounds__(256) void k_fin(
    const float* __restrict__ acc, const float* __restrict__ wsM,
    const float* __restrict__ wsL, float* __restrict__ out, int NC)
{
    const float LN2 = 0.6931471805599453f;
    __shared__ float red[4];
    int lane = threadIdx.x & 63;
    int wv   = threadIdx.x >> 6;
    int i    = blockIdx.x * 4 + wv;

    // log_qz_product (log2 units): lane owns dimension d = lane
    float s = 0.0f;
    for (int c = 0; c < NC; ++c) s += acc[c * (B * D) + i * D + lane];
    float lqp2 = log2fast(s);
#pragma unroll
    for (int off = 32; off; off >>= 1) lqp2 += __shfl_xor(lqp2, off);

    // log_qz: merge chunk-level (M, L) pairs; lane owns chunk c = lane
    float m = -3.0e38f, l = 0.0f;
    if (lane < NC) { m = wsM[i * NC + lane]; l = wsL[i * NC + lane]; }
#pragma unroll
    for (int off = 32; off; off >>= 1) {
        float m2 = __shfl_xor(m, off);
        float l2 = __shfl_xor(l, off);
        float M  = fmaxf(m, m2);
        l = fmaf(l, exp2fast(m - M), l2 * exp2fast(m2 - M));
        m = M;
    }

    if (lane == 0)
        red[wv] = (m + log2fast(l) - lqp2) * LN2;  // ln(qz) - ln(qz_product)
    __syncthreads();
    if (threadIdx.x == 0)
        atomicAdd(out, (red[0] + red[1] + red[2] + red[3]) * (5.0f / 2048.0f));
}

// ---------------------------------------------------------------------------
extern "C" void kernel_launch(void* const* d_in, const int* in_sizes, int n_in,
                              void* d_out, int out_size, void* d_ws, size_t ws_size,
                              hipStream_t stream)
{
    const float* kl  = (const float*)d_in[0];
    const float* zm  = (const float*)d_in[1];
    const float* zlv = (const float*)d_in[2];
    const float* zs  = (const float*)d_in[3];
    float* out = (float*)d_out;
    float* ws  = (float*)d_ws;

    // pick j-chunk count NC (power of two) that fits the workspace
    size_t wsFloats = ws_size / sizeof(float);
    int NC = 16;
    while (NC > 1) {
        size_t need = (size_t)4 * B * D        // pack4
                    + (size_t)2 * B * D        // pack2
                    + B                        // C2
                    + (size_t)2 * B * NC       // wsM + wsL
                    + (size_t)NC * B * D;      // acc partials
        if (need <= wsFloats) break;
        NC >>= 1;
    }
    int ncShift = 0;
    while ((1 << ncShift) < NC) ++ncShift;

    float4* pack4 = (float4*)ws;                      // 4*B*D floats
    float2* pack2 = (float2*)(ws + 4 * B * D);        // 2*B*D floats
    float*  C2    = ws + 6 * B * D;                   // B floats
    float*  wsM   = C2 + B;                           // B*NC
    float*  wsL   = wsM + (size_t)B * NC;             // B*NC
    float*  acc   = wsL + (size_t)B * NC;             // NC*B*D

    hipMemsetAsync(d_out, 0, sizeof(float), stream);
    k_pre<<<B / 4, 256, 0, stream>>>(kl, zm, zlv, pack4, pack2, C2, out);
    k_main<<<64 * NC, 256, 0, stream>>>(zs, pack4, pack2, C2, acc, wsM, wsL, NC, ncShift);
    k_fin<<<B / 4, 256, 0, stream>>>(acc, wsM, wsL, out, NC);
}

// Round 4
// 97.199 us; speedup vs baseline: 2.9760x; 1.3135x over previous
//
#include <hip/hip_runtime.h>
#include <math.h>

#define B 2048
#define D 64
#define IT 8
#define NC 32
#define CJ (B / NC)   // 64

static __device__ __forceinline__ float exp2fast(float x) { return __builtin_amdgcn_exp2f(x); }
static __device__ __forceinline__ float log2fast(float x) { return __builtin_amdgcn_logf(x); }

// ---------------------------------------------------------------------------
// Kernel 1: precompute packed per-(j,d) constants, C2[j], kl sum; zero acc.
// All in log2 units:  lp2 = h*(z-mu)^2 + c  =  h*z^2 + g*z + q
//   h = -0.5*log2e*exp(-lv),  g = -2*mu*h,  q = mu^2*h + c,
//   c = -0.5*log2e*(lv + ln(2*pi))
//   pack4[j*D+d] = (h, g, q, 0)   row-major, for loop 1
//   pack2[d*B+j] = (mu, h)        transposed, for loop 2
//   C2[j] = sum_d c
// Grid is exactly B*D threads; thread gid also zeroes acc[gid].
// ---------------------------------------------------------------------------
__global__ __launch_bounds__(256) void k_pre(
    const float* __restrict__ kl, const float* __restrict__ zm,
    const float* __restrict__ zlv,
    float4* __restrict__ pack4, float2* __restrict__ pack2,
    float* __restrict__ C2, float* __restrict__ acc, float* __restrict__ out)
{
    const float LOG2E   = 1.4426950408889634f;
    const float LOG_2PI = 1.8378770664093453f;
    __shared__ float red[4];
    int wv = threadIdx.x >> 6, d = threadIdx.x & 63;
    int j = blockIdx.x * 4 + wv;
    int idx = j * D + d;
    acc[idx] = 0.0f;                             // zero merged accumulator
    float lv = zlv[idx];
    float mu = zm[idx];
    float is = exp2fast(-LOG2E * lv);            // e^{-lv}
    float h  = -0.5f * LOG2E * is;
    float cv = -0.5f * LOG2E * (lv + LOG_2PI);
    float g  = -2.0f * mu * h;
    float q  = fmaf(mu * mu, h, cv);
    pack4[idx]       = make_float4(h, g, q, 0.0f);
    pack2[d * B + j] = make_float2(mu, h);

    float cs = cv, ks = kl[idx];
#pragma unroll
    for (int off = 32; off; off >>= 1) {
        cs += __shfl_xor(cs, off);
        ks += __shfl_xor(ks, off);
    }
    if (d == 0) {
        C2[j] = cs;
        red[wv] = ks;
    }
    __syncthreads();
    if (threadIdx.x == 0)
        atomicAdd(out, red[0] + red[1] + red[2] + red[3]);  // kl_loss
}

// ---------------------------------------------------------------------------
// Kernel 2: 2048x2048x64 workhorse. One wave = IT=8 rows i, one j-chunk of 64.
// Block's 4 waves share the SAME chunk (L1 reuse of pack4/pack2) and own
// consecutive igroups.
//   Loop 1 (lanes own d): a_d[i] = sum_j 2^{h z^2 + g z + q}  -> atomicAdd acc
//   Loop 2 (lanes own j, single 64-j group): s2_j[i] = C2_j + sum_d t*t*h,
//          then wave butterfly-LSE -> (M,L) per (i,chunk).
// ---------------------------------------------------------------------------
__global__ __launch_bounds__(256) void k_main(
    const float* __restrict__ z, const float4* __restrict__ pack4,
    const float2* __restrict__ pack2, const float* __restrict__ C2,
    float* __restrict__ acc, float* __restrict__ wsM, float* __restrict__ wsL)
{
    int lane   = threadIdx.x & 63;
    int wv     = threadIdx.x >> 6;
    int chunk  = blockIdx.x & (NC - 1);
    int igroup = (blockIdx.x >> 5) * 4 + wv;
    int i0     = igroup * IT;
    int j0     = chunk * CJ;

    float zr[IT], zr2[IT], a[IT];
#pragma unroll
    for (int k = 0; k < IT; ++k) {
        zr[k]  = z[(i0 + k) * D + lane];
        zr2[k] = zr[k] * zr[k];
        a[k]   = 0.0f;
    }

    // ---- Loop 1: per-dimension sum of exponentials (lanes = d) ----
#pragma unroll 2
    for (int j = j0; j < j0 + CJ; ++j) {
        float4 p = pack4[j * D + lane];
#pragma unroll
        for (int k = 0; k < IT; ++k)
            a[k] += exp2fast(fmaf(zr2[k], p.x, fmaf(zr[k], p.y, p.z)));
    }
#pragma unroll
    for (int k = 0; k < IT; ++k)
        atomicAdd(&acc[(i0 + k) * D + lane], a[k]);

    // ---- Loop 2: per-(i,j) row sums over d (lanes = j) ----
    int jj = j0 + lane;
    float c2j = C2[jj];
    float s2[IT];
#pragma unroll
    for (int k = 0; k < IT; ++k) s2[k] = c2j;

    for (int d = 0; d < D; ++d) {
        float2 p = pack2[d * B + jj];
#pragma unroll
        for (int k = 0; k < IT; ++k) {
            float zv = __uint_as_float(
                __builtin_amdgcn_readlane(__float_as_uint(zr[k]), d));
            float t = zv - p.x;
            s2[k] = fmaf(t * t, p.y, s2[k]);
        }
    }

    // wave-level LSE merge (butterfly); per-lane state is (m=s2, l=1)
    float m[IT], l[IT];
#pragma unroll
    for (int k = 0; k < IT; ++k) { m[k] = s2[k]; l[k] = 1.0f; }
#pragma unroll
    for (int off = 32; off; off >>= 1) {
#pragma unroll
        for (int k = 0; k < IT; ++k) {
            float m2 = __shfl_xor(m[k], off);
            float l2 = __shfl_xor(l[k], off);
            float M  = fmaxf(m[k], m2);
            l[k] = fmaf(l[k], exp2fast(m[k] - M), l2 * exp2fast(m2 - M));
            m[k] = M;
        }
    }
    if (lane == 0) {
#pragma unroll
        for (int k = 0; k < IT; ++k) {
            wsM[(i0 + k) * NC + chunk] = m[k];
            wsL[(i0 + k) * NC + chunk] = l[k];
        }
    }
}

// ---------------------------------------------------------------------------
// Kernel 3: per-i finalization, one WAVE per i (512 blocks x 256 threads).
//   lanes own d: log2(acc), butterfly-sum -> lqp2
//   lanes own c: merge chunk (M,L) pairs via butterfly LSE
//   block LDS reduce -> 1 atomic per block
// ---------------------------------------------------------------------------
__global__ __launch_bounds__(256) void k_fin(
    const float* __restrict__ acc, const float* __restrict__ wsM,
    const float* __restrict__ wsL, float* __restrict__ out)
{
    const float LN2 = 0.6931471805599453f;
    __shared__ float red[4];
    int lane = threadIdx.x & 63;
    int wv   = threadIdx.x >> 6;
    int i    = blockIdx.x * 4 + wv;

    // log_qz_product (log2 units): lane owns dimension d = lane
    float lqp2 = log2fast(acc[i * D + lane]);
#pragma unroll
    for (int off = 32; off; off >>= 1) lqp2 += __shfl_xor(lqp2, off);

    // log_qz: merge chunk-level (M, L) pairs; lane owns chunk c = lane
    float m = -3.0e38f, l = 0.0f;
    if (lane < NC) { m = wsM[i * NC + lane]; l = wsL[i * NC + lane]; }
#pragma unroll
    for (int off = 32; off; off >>= 1) {
        float m2 = __shfl_xor(m, off);
        float l2 = __shfl_xor(l, off);
        float M  = fmaxf(m, m2);
        l = fmaf(l, exp2fast(m - M), l2 * exp2fast(m2 - M));
        m = M;
    }

    if (lane == 0)
        red[wv] = (m + log2fast(l) - lqp2) * LN2;  // ln(qz) - ln(qz_product)
    __syncthreads();
    if (threadIdx.x == 0)
        atomicAdd(out, (red[0] + red[1] + red[2] + red[3]) * (5.0f / 2048.0f));
}

// ---------------------------------------------------------------------------
extern "C" void kernel_launch(void* const* d_in, const int* in_sizes, int n_in,
                              void* d_out, int out_size, void* d_ws, size_t ws_size,
                              hipStream_t stream)
{
    const float* kl  = (const float*)d_in[0];
    const float* zm  = (const float*)d_in[1];
    const float* zlv = (const float*)d_in[2];
    const float* zs  = (const float*)d_in[3];
    float* out = (float*)d_out;
    float* ws  = (float*)d_ws;

    // workspace layout (floats): 4BD + 2BD + B + B*NC + B*NC + BD  ~= 4.7 MB
    float4* pack4 = (float4*)ws;                      // 4*B*D
    float2* pack2 = (float2*)(ws + 4 * B * D);        // 2*B*D
    float*  C2    = ws + 6 * B * D;                   // B
    float*  wsM   = C2 + B;                           // B*NC
    float*  wsL   = wsM + (size_t)B * NC;             // B*NC
    float*  acc   = wsL + (size_t)B * NC;             // B*D (atomic-merged)

    hipMemsetAsync(d_out, 0, sizeof(float), stream);
    k_pre<<<B / 4, 256, 0, stream>>>(kl, zm, zlv, pack4, pack2, C2, acc, out);
    k_main<<<(B / IT / 4) * NC, 256, 0, stream>>>(zs, pack4, pack2, C2, acc, wsM, wsL);
    k_fin<<<B / 4, 256, 0, stream>>>(acc, wsM, wsL, out);
}

// Round 5
// 75.558 us; speedup vs baseline: 3.8284x; 1.2864x over previous
//
#include <hip/hip_runtime.h>
#include <math.h>

#define B 2048
#define D 64
#define IT 8
#define NCH 32          // j-chunks for loop-1 kernel
#define CJ (B / NCH)    // 64
#define NC2 16          // j-chunks for the MFMA/LSE kernel

typedef float v2f  __attribute__((ext_vector_type(2)));
typedef short bf16x8 __attribute__((ext_vector_type(8)));
typedef float f32x4  __attribute__((ext_vector_type(4)));

static __device__ __forceinline__ float exp2fast(float x) { return __builtin_amdgcn_exp2f(x); }
static __device__ __forceinline__ float log2fast(float x) { return __builtin_amdgcn_logf(x); }
static __device__ __forceinline__ unsigned short f2bf(float x) {
    unsigned u = __float_as_uint(x);
    u += 0x7fff + ((u >> 16) & 1);          // RNE; inputs are finite
    return (unsigned short)(u >> 16);
}

// ---------------------------------------------------------------------------
// Kernel 1: per-(j,d) constants (log2 units):  lp2 = h*z^2 + g*z + q
//   h = -0.5*log2e*exp(-lv), g = -2*mu*h, q = mu^2*h + c,
//   c = -0.5*log2e*(lv + ln 2pi)
// Outputs:
//   pack4[j*D+d] = (h,g,q,0)                     fp32, loop-1 operand
//   Wt[j][0:64]=bf16(h), Wt[j][64:128]=bf16(g)   MFMA B operand (row-major K)
//   Zx[i][0:64]=bf16(z^2), Zx[i][64:128]=bf16(z) MFMA A operand
//   QQ[j] = sum_d q                              fp32 epilogue constant
//   acc zeroed; kl block-reduced -> 1 atomic.
// ---------------------------------------------------------------------------
__global__ __launch_bounds__(256) void k_pre(
    const float* __restrict__ kl, const float* __restrict__ zm,
    const float* __restrict__ zlv, const float* __restrict__ zs,
    float4* __restrict__ pack4, unsigned short* __restrict__ Zx,
    unsigned short* __restrict__ Wt, float* __restrict__ QQ,
    float* __restrict__ acc, float* __restrict__ out)
{
    const float LOG2E   = 1.4426950408889634f;
    const float LOG_2PI = 1.8378770664093453f;
    __shared__ float red[4];
    int wv = threadIdx.x >> 6, d = threadIdx.x & 63;
    int j = blockIdx.x * 4 + wv;
    int idx = j * D + d;
    acc[idx] = 0.0f;
    float lv = zlv[idx];
    float mu = zm[idx];
    float zz = zs[idx];
    float is = exp2fast(-LOG2E * lv);            // e^{-lv}
    float h  = -0.5f * LOG2E * is;
    float cv = -0.5f * LOG2E * (lv + LOG_2PI);
    float g  = -2.0f * mu * h;
    float q  = fmaf(mu * mu, h, cv);
    pack4[idx] = make_float4(h, g, q, 0.0f);
    Wt[j * 128 + d]      = f2bf(h);
    Wt[j * 128 + 64 + d] = f2bf(g);
    Zx[j * 128 + d]      = f2bf(zz * zz);
    Zx[j * 128 + 64 + d] = f2bf(zz);

    float qs = q, ks = kl[idx];
#pragma unroll
    for (int off = 32; off; off >>= 1) {
        qs += __shfl_xor(qs, off);
        ks += __shfl_xor(ks, off);
    }
    if (d == 0) { QQ[j] = qs; red[wv] = ks; }
    __syncthreads();
    if (threadIdx.x == 0)
        atomicAdd(out, red[0] + red[1] + red[2] + red[3]);  // kl_loss
}

// ---------------------------------------------------------------------------
// Kernel 2: loop 1 only — acc[i][d] = sum_j 2^(h z^2 + g z + q).
// One wave = 8 rows i (as 4 float2 pairs), one 64-j chunk; lanes own d.
// Packed fp32 (v_pk_fma/v_pk_add) + 2 exp2 per float2 pair.
// ---------------------------------------------------------------------------
__global__ __launch_bounds__(256) void k_main(
    const float* __restrict__ z, const float4* __restrict__ pack4,
    float* __restrict__ acc)
{
    int lane   = threadIdx.x & 63;
    int wv     = threadIdx.x >> 6;
    int chunk  = blockIdx.x & (NCH - 1);
    int igroup = (blockIdx.x >> 5) * 4 + wv;
    int i0     = igroup * IT;
    int j0     = chunk * CJ;

    v2f zrp[4], zr2p[4], ap[4];
#pragma unroll
    for (int kp = 0; kp < 4; ++kp) {
        float za = z[(i0 + 2 * kp) * D + lane];
        float zb = z[(i0 + 2 * kp + 1) * D + lane];
        zrp[kp]  = (v2f){za, zb};
        zr2p[kp] = (v2f){za * za, zb * zb};
        ap[kp]   = (v2f){0.0f, 0.0f};
    }

#pragma unroll 2
    for (int j = j0; j < j0 + CJ; ++j) {
        float4 p = pack4[j * D + lane];
        v2f hh = (v2f){p.x, p.x};
        v2f gg = (v2f){p.y, p.y};
        v2f qq = (v2f){p.z, p.z};
#pragma unroll
        for (int kp = 0; kp < 4; ++kp) {
            v2f arg = zr2p[kp] * hh + (zrp[kp] * gg + qq);  // 2x v_pk_fma_f32
            v2f e;
            e.x = exp2fast(arg.x);
            e.y = exp2fast(arg.y);
            ap[kp] += e;                                    // v_pk_add_f32
        }
    }
#pragma unroll
    for (int kp = 0; kp < 4; ++kp) {
        atomicAdd(&acc[(i0 + 2 * kp) * D + lane], ap[kp].x);
        atomicAdd(&acc[(i0 + 2 * kp + 1) * D + lane], ap[kp].y);
    }
}

// ---------------------------------------------------------------------------
// Kernel 3: s2[i][j] = QQ_j + sum_k Zx[i][k]*Wt[j][k]  via 16x16x32 bf16 MFMA,
// with the row-LSE over j fused into the epilogue.
// 512 blocks x 256: block = 16-i block x 512-j chunk; wave = 128-j subchunk
// (8 tiles of 16 j, K=128 = 4 mfma steps). Fragment rule (both operands):
// lane&15 = M/N index, (lane>>4)*8 = K offset, 8 K-contiguous bf16.
// C/D: col = lane&15 (j), row = (lane>>4)*4 + reg (i)  [m89-verified].
// ---------------------------------------------------------------------------
__global__ __launch_bounds__(256) void k_lse(
    const unsigned short* __restrict__ Zx, const unsigned short* __restrict__ Wt,
    const float* __restrict__ QQ, float* __restrict__ wsM, float* __restrict__ wsL)
{
    int lane  = threadIdx.x & 63;
    int wv    = threadIdx.x >> 6;
    int i0    = (blockIdx.x >> 2) * 16;
    int chunk = (blockIdx.x & 3) * 4 + wv;     // 0..15
    int jbase = chunk * 128;
    int r16 = lane & 15, kg = lane >> 4;

    const bf16x8* Za = (const bf16x8*)(Zx + (size_t)(i0 + r16) * 128 + kg * 8);
    bf16x8 a[4];
#pragma unroll
    for (int s = 0; s < 4; ++s) a[s] = Za[s * 4];   // stride 32 bf16 per K-step

    float m[4], l[4];
#pragma unroll
    for (int r = 0; r < 4; ++r) { m[r] = -3.0e38f; l[r] = 0.0f; }

    for (int t = 0; t < 8; ++t) {
        int j = jbase + t * 16 + r16;
        const bf16x8* Wb = (const bf16x8*)(Wt + (size_t)j * 128 + kg * 8);
        f32x4 c = (f32x4){0.0f, 0.0f, 0.0f, 0.0f};
#pragma unroll
        for (int s = 0; s < 4; ++s)
            c = __builtin_amdgcn_mfma_f32_16x16x32_bf16(a[s], Wb[s * 4], c, 0, 0, 0);
        float qq = QQ[j];
#pragma unroll
        for (int r = 0; r < 4; ++r) {
            float val = c[r] + qq;
            float delta = val - m[r];
            float e = exp2fast(-fabsf(delta));
            l[r] = (delta <= 0.0f) ? (l[r] + e) : fmaf(l[r], e, 1.0f);
            m[r] = fmaxf(m[r], val);
        }
    }
    // merge the 16 columns (j) held by lanes within each 16-lane group
#pragma unroll
    for (int off = 8; off; off >>= 1) {
#pragma unroll
        for (int r = 0; r < 4; ++r) {
            float m2 = __shfl_xor(m[r], off);
            float l2 = __shfl_xor(l[r], off);
            float M  = fmaxf(m[r], m2);
            l[r] = fmaf(l[r], exp2fast(m[r] - M), l2 * exp2fast(m2 - M));
            m[r] = M;
        }
    }
    if (r16 == 0) {
#pragma unroll
        for (int r = 0; r < 4; ++r) {
            int i = i0 + kg * 4 + r;
            wsM[i * NC2 + chunk] = m[r];
            wsL[i * NC2 + chunk] = l[r];
        }
    }
}

// ---------------------------------------------------------------------------
// Kernel 4: per-i finalization, one wave per i.
// ---------------------------------------------------------------------------
__global__ __launch_bounds__(256) void k_fin(
    const float* __restrict__ acc, const float* __restrict__ wsM,
    const float* __restrict__ wsL, float* __restrict__ out)
{
    const float LN2 = 0.6931471805599453f;
    __shared__ float red[4];
    int lane = threadIdx.x & 63;
    int wv   = threadIdx.x >> 6;
    int i    = blockIdx.x * 4 + wv;

    float lqp2 = log2fast(acc[i * D + lane]);
#pragma unroll
    for (int off = 32; off; off >>= 1) lqp2 += __shfl_xor(lqp2, off);

    float m = -3.0e38f, l = 0.0f;
    if (lane < NC2) { m = wsM[i * NC2 + lane]; l = wsL[i * NC2 + lane]; }
#pragma unroll
    for (int off = 32; off; off >>= 1) {
        float m2 = __shfl_xor(m, off);
        float l2 = __shfl_xor(l, off);
        float M  = fmaxf(m, m2);
        l = fmaf(l, exp2fast(m - M), l2 * exp2fast(m2 - M));
        m = M;
    }

    if (lane == 0)
        red[wv] = (m + log2fast(l) - lqp2) * LN2;
    __syncthreads();
    if (threadIdx.x == 0)
        atomicAdd(out, (red[0] + red[1] + red[2] + red[3]) * (5.0f / 2048.0f));
}

// ---------------------------------------------------------------------------
extern "C" void kernel_launch(void* const* d_in, const int* in_sizes, int n_in,
                              void* d_out, int out_size, void* d_ws, size_t ws_size,
                              hipStream_t stream)
{
    const float* kl  = (const float*)d_in[0];
    const float* zm  = (const float*)d_in[1];
    const float* zlv = (const float*)d_in[2];
    const float* zs  = (const float*)d_in[3];
    float* out = (float*)d_out;
    float* ws  = (float*)d_ws;

    // workspace layout (floats)
    float4*         pack4 = (float4*)ws;                         // 4*B*D
    unsigned short* Zx    = (unsigned short*)(ws + 4 * B * D);   // B*128 u16 = B*64 f32
    unsigned short* Wt    = (unsigned short*)(ws + 4 * B * D + (B * 128) / 2);
    float*          QQ    = ws + 4 * B * D + B * 128;            // B
    float*          wsM   = QQ + B;                              // B*NC2
    float*          wsL   = wsM + (size_t)B * NC2;               // B*NC2
    float*          acc   = wsL + (size_t)B * NC2;               // B*D

    hipMemsetAsync(d_out, 0, sizeof(float), stream);
    k_pre<<<B / 4, 256, 0, stream>>>(kl, zm, zlv, zs, pack4, Zx, Wt, QQ, acc, out);
    k_main<<<(B / IT / 4) * NCH, 256, 0, stream>>>(zs, pack4, acc);
    k_lse<<<(B / 16) * 4, 256, 0, stream>>>(Zx, Wt, QQ, wsM, wsL);
    k_fin<<<B / 4, 256, 0, stream>>>(acc, wsM, wsL, out);
}

// Round 7
// 72.851 us; speedup vs baseline: 3.9707x; 1.0372x over previous
//
#include <hip/hip_runtime.h>
#include <math.h>

#define B 2048
#define D 64
#define IT 16           // i-rows per wave in loop-1 role
#define NCH 32          // j-chunks for loop-1 role
#define CJ (B / NCH)    // 64
#define NC2 16          // j-chunks for the MFMA/LSE role
#define GRID_MAIN (B / IT / 4 * NCH)   // 1024 main blocks
#define GRID_LSE  ((B / 16) * 4)       // 512 lse blocks
// grouping: 512 groups x {2 main, 1 lse} = 1536 blocks total

typedef float v2f  __attribute__((ext_vector_type(2)));
typedef short bf16x8 __attribute__((ext_vector_type(8)));
typedef float f32x4  __attribute__((ext_vector_type(4)));

static __device__ __forceinline__ float exp2fast(float x) { return __builtin_amdgcn_exp2f(x); }
static __device__ __forceinline__ float log2fast(float x) { return __builtin_amdgcn_logf(x); }
static __device__ __forceinline__ unsigned short f2bf(float x) {
    unsigned u = __float_as_uint(x);
    u += 0x7fff + ((u >> 16) & 1);          // RNE; inputs are finite
    return (unsigned short)(u >> 16);
}

// ---------------------------------------------------------------------------
// Kernel 1: per-(j,d) constants (log2 units):  lp2 = h*z^2 + g*z + q
//   h = -0.5*log2e*exp(-lv), g = -2*mu*h, q = mu^2*h + c,
//   c = -0.5*log2e*(lv + ln 2pi)
// Outputs: pack4 (fp32, loop-1), Zx/Wt (bf16 MFMA operands), QQ[j]=sum_d q,
// acc zeroed, kl block-reduced -> 1 atomic.
// ---------------------------------------------------------------------------
__global__ __launch_bounds__(256) void k_pre(
    const float* __restrict__ kl, const float* __restrict__ zm,
    const float* __restrict__ zlv, const float* __restrict__ zs,
    float4* __restrict__ pack4, unsigned short* __restrict__ Zx,
    unsigned short* __restrict__ Wt, float* __restrict__ QQ,
    float* __restrict__ acc, float* __restrict__ out)
{
    const float LOG2E   = 1.4426950408889634f;
    const float LOG_2PI = 1.8378770664093453f;
    __shared__ float red[4];
    int wv = threadIdx.x >> 6, d = threadIdx.x & 63;
    int j = blockIdx.x * 4 + wv;
    int idx = j * D + d;
    acc[idx] = 0.0f;
    float lv = zlv[idx];
    float mu = zm[idx];
    float zz = zs[idx];
    float is = exp2fast(-LOG2E * lv);            // e^{-lv}
    float h  = -0.5f * LOG2E * is;
    float cv = -0.5f * LOG2E * (lv + LOG_2PI);
    float g  = -2.0f * mu * h;
    float q  = fmaf(mu * mu, h, cv);
    pack4[idx] = make_float4(h, g, q, 0.0f);
    Wt[j * 128 + d]      = f2bf(h);
    Wt[j * 128 + 64 + d] = f2bf(g);
    Zx[j * 128 + d]      = f2bf(zz * zz);
    Zx[j * 128 + 64 + d] = f2bf(zz);

    float qs = q, ks = kl[idx];
#pragma unroll
    for (int off = 32; off; off >>= 1) {
        qs += __shfl_xor(qs, off);
        ks += __shfl_xor(ks, off);
    }
    if (d == 0) { QQ[j] = qs; red[wv] = ks; }
    __syncthreads();
    if (threadIdx.x == 0)
        atomicAdd(out, red[0] + red[1] + red[2] + red[3]);  // kl_loss
}

// ---------------------------------------------------------------------------
// Role A (main): acc[i][d] += sum_j 2^(h z^2 + g z + q); wave = IT=16 rows i
// (8 float2 pairs), one 64-j chunk, lanes own d. Packed fp32 FMA + exp2.
// ---------------------------------------------------------------------------
static __device__ __forceinline__ void role_main(
    int mb, const float* __restrict__ z, const float4* __restrict__ pack4,
    float* __restrict__ acc)
{
    int lane   = threadIdx.x & 63;
    int wv     = threadIdx.x >> 6;
    int chunk  = mb & (NCH - 1);
    int igroup = (mb >> 5) * 4 + wv;
    int i0     = igroup * IT;
    int j0     = chunk * CJ;

    v2f zrp[IT / 2], zr2p[IT / 2], ap[IT / 2];
#pragma unroll
    for (int kp = 0; kp < IT / 2; ++kp) {
        float za = z[(i0 + 2 * kp) * D + lane];
        float zb = z[(i0 + 2 * kp + 1) * D + lane];
        zrp[kp]  = (v2f){za, zb};
        zr2p[kp] = (v2f){za * za, zb * zb};
        ap[kp]   = (v2f){0.0f, 0.0f};
    }

#pragma unroll 2
    for (int j = j0; j < j0 + CJ; ++j) {
        float4 p = pack4[j * D + lane];
        v2f hh = (v2f){p.x, p.x};
        v2f gg = (v2f){p.y, p.y};
        v2f qq = (v2f){p.z, p.z};
#pragma unroll
        for (int kp = 0; kp < IT / 2; ++kp) {
            v2f arg = zr2p[kp] * hh + (zrp[kp] * gg + qq);  // 2x v_pk_fma_f32
            v2f e;
            e.x = exp2fast(arg.x);
            e.y = exp2fast(arg.y);
            ap[kp] += e;                                    // v_pk_add_f32
        }
    }
#pragma unroll
    for (int kp = 0; kp < IT / 2; ++kp) {
        atomicAdd(&acc[(i0 + 2 * kp) * D + lane], ap[kp].x);
        atomicAdd(&acc[(i0 + 2 * kp + 1) * D + lane], ap[kp].y);
    }
}

// ---------------------------------------------------------------------------
// Role B (lse): s2[i][j] = QQ_j + sum_k Zx[i][k]*Wt[j][k] via 16x16x32 bf16
// MFMA, row-LSE over j fused in epilogue. Block = 16-i x 512-j; wave = 128-j.
// C/D: col = lane&15 (j), row = (lane>>4)*4 + reg (i)  [m89-verified].
// ---------------------------------------------------------------------------
static __device__ __forceinline__ void role_lse(
    int lb, const unsigned short* __restrict__ Zx,
    const unsigned short* __restrict__ Wt, const float* __restrict__ QQ,
    float* __restrict__ wsM, float* __restrict__ wsL)
{
    int lane  = threadIdx.x & 63;
    int wv    = threadIdx.x >> 6;
    int i0    = (lb >> 2) * 16;
    int chunk = (lb & 3) * 4 + wv;     // 0..15
    int jbase = chunk * 128;
    int r16 = lane & 15, kg = lane >> 4;

    const bf16x8* Za = (const bf16x8*)(Zx + (size_t)(i0 + r16) * 128 + kg * 8);
    bf16x8 a[4];
#pragma unroll
    for (int s = 0; s < 4; ++s) a[s] = Za[s * 4];   // stride 32 bf16 per K-step

    float m[4], l[4];
#pragma unroll
    for (int r = 0; r < 4; ++r) { m[r] = -3.0e38f; l[r] = 0.0f; }

    for (int t = 0; t < 8; ++t) {
        int j = jbase + t * 16 + r16;
        const bf16x8* Wb = (const bf16x8*)(Wt + (size_t)j * 128 + kg * 8);
        f32x4 c = (f32x4){0.0f, 0.0f, 0.0f, 0.0f};
#pragma unroll
        for (int s = 0; s < 4; ++s)
            c = __builtin_amdgcn_mfma_f32_16x16x32_bf16(a[s], Wb[s * 4], c, 0, 0, 0);
        float qq = QQ[j];
#pragma unroll
        for (int r = 0; r < 4; ++r) {
            float val = c[r] + qq;
            float delta = val - m[r];
            float e = exp2fast(-fabsf(delta));
            l[r] = (delta <= 0.0f) ? (l[r] + e) : fmaf(l[r], e, 1.0f);
            m[r] = fmaxf(m[r], val);
        }
    }
#pragma unroll
    for (int off = 8; off; off >>= 1) {
#pragma unroll
        for (int r = 0; r < 4; ++r) {
            float m2 = __shfl_xor(m[r], off);
            float l2 = __shfl_xor(l[r], off);
            float M  = fmaxf(m[r], m2);
            l[r] = fmaf(l[r], exp2fast(m[r] - M), l2 * exp2fast(m2 - M));
            m[r] = M;
        }
    }
    if (r16 == 0) {
#pragma unroll
        for (int r = 0; r < 4; ++r) {
            int i = i0 + kg * 4 + r;
            wsM[i * NC2 + chunk] = m[r];
            wsL[i * NC2 + chunk] = l[r];
        }
    }
}

// ---------------------------------------------------------------------------
// Kernel 2: fused mega-kernel. 512 groups of {2 main, 1 lse} = 1536 blocks,
// so both roles co-reside on each CU (LSE's MFMA/VMEM fills loop-1's slack).
// main ids: bq*2+br in [0,1024); lse ids: bq in [0,512).
// ---------------------------------------------------------------------------
__global__ __launch_bounds__(256) void k_mega(
    const float* __restrict__ z, const float4* __restrict__ pack4,
    float* __restrict__ acc, const unsigned short* __restrict__ Zx,
    const unsigned short* __restrict__ Wt, const float* __restrict__ QQ,
    float* __restrict__ wsM, float* __restrict__ wsL)
{
    unsigned bq = blockIdx.x / 3, br = blockIdx.x % 3;
    if (br == 2)
        role_lse(bq, Zx, Wt, QQ, wsM, wsL);
    else
        role_main(bq * 2 + br, z, pack4, acc);
}

// ---------------------------------------------------------------------------
// Kernel 3: per-i finalization, one wave per i.
// ---------------------------------------------------------------------------
__global__ __launch_bounds__(256) void k_fin(
    const float* __restrict__ acc, const float* __restrict__ wsM,
    const float* __restrict__ wsL, float* __restrict__ out)
{
    const float LN2 = 0.6931471805599453f;
    __shared__ float red[4];
    int lane = threadIdx.x & 63;
    int wv   = threadIdx.x >> 6;
    int i    = blockIdx.x * 4 + wv;

    float lqp2 = log2fast(acc[i * D + lane]);
#pragma unroll
    for (int off = 32; off; off >>= 1) lqp2 += __shfl_xor(lqp2, off);

    float m = -3.0e38f, l = 0.0f;
    if (lane < NC2) { m = wsM[i * NC2 + lane]; l = wsL[i * NC2 + lane]; }
#pragma unroll
    for (int off = 32; off; off >>= 1) {
        float m2 = __shfl_xor(m, off);
        float l2 = __shfl_xor(l, off);
        float M  = fmaxf(m, m2);
        l = fmaf(l, exp2fast(m - M), l2 * exp2fast(m2 - M));
        m = M;
    }

    if (lane == 0)
        red[wv] = (m + log2fast(l) - lqp2) * LN2;
    __syncthreads();
    if (threadIdx.x == 0)
        atomicAdd(out, (red[0] + red[1] + red[2] + red[3]) * (5.0f / 2048.0f));
}

// ---------------------------------------------------------------------------
extern "C" void kernel_launch(void* const* d_in, const int* in_sizes, int n_in,
                              void* d_out, int out_size, void* d_ws, size_t ws_size,
                              hipStream_t stream)
{
    const float* kl  = (const float*)d_in[0];
    const float* zm  = (const float*)d_in[1];
    const float* zlv = (const float*)d_in[2];
    const float* zs  = (const float*)d_in[3];
    float* out = (float*)d_out;
    float* ws  = (float*)d_ws;

    // workspace layout (floats)
    float4*         pack4 = (float4*)ws;                         // 4*B*D
    unsigned short* Zx    = (unsigned short*)(ws + 4 * B * D);   // B*128 u16
    unsigned short* Wt    = (unsigned short*)(ws + 4 * B * D + (B * 128) / 2);
    float*          QQ    = ws + 4 * B * D + B * 128;            // B
    float*          wsM   = QQ + B;                              // B*NC2
    float*          wsL   = wsM + (size_t)B * NC2;               // B*NC2
    float*          acc   = wsL + (size_t)B * NC2;               // B*D

    hipMemsetAsync(d_out, 0, sizeof(float), stream);
    k_pre<<<B / 4, 256, 0, stream>>>(kl, zm, zlv, zs, pack4, Zx, Wt, QQ, acc, out);
    k_mega<<<1536, 256, 0, stream>>>(zs, pack4, acc, Zx, Wt, QQ, wsM, wsL);
    k_fin<<<B / 4, 256, 0, stream>>>(acc, wsM, wsL, out);
}